// Round 5
// baseline (785.699 us; speedup 1.0000x reference)
//
#include <hip/hip_runtime.h>
#include <math.h>

// ---------------------------------------------------------------------------
// LongRec.  B=256, S=200, D=U=128, NC=50000.
// alpha = softmax over singleton axis == 1.0 -> h_att = h_d; W_a is dead.
// Pipeline:
//   k0  : 14 x [128][128] fp32 -> bf16 k-swizzled (B-frag layout; slots 11-13
//         are W_hr/W_hz/W_hh which k3 reads as A-frags of W^T — same swizzle).
//   k12 : MFMA precompute -> PRE fp32 (reg A-frag gather; fast sigmoid epilog).
//   k3  : R10: 16 batch rows per wg (16 wgs x 256 thr = 4 waves), recurrence
//         matvecs as 16x128x128 bf16 MFMA GEMMs.  Recurrent state master is
//         fp32 in registers (C-layout: lane=batch, regs=dims); only MFMA
//         inputs rounded to bf16.  State shared via XOR-swizzled LDS B-frags.
//         2 lgkm barriers/step; PRE constants prefetched 1 step ahead with
//         in-place register rotation.
//   k0b : W_out -> bf16 WT[n][k]  (aliases PRE, dead after k3)
//   k4a : logits = h @ W_out + b_out via bf16 MFMA
//   k4b/c: row stats, softmax normalize
// ---------------------------------------------------------------------------

#define B_  256
#define S_  200
#define U_  128
#define NC  50000
#define NTOK (B_ * S_)       // 51200

// ws layout (in floats)
#define PRE_OFF   0
#define PRE_SZ    (NTOK * 768)            // 39321600 floats
#define LOG_OFF   PRE_SZ                  // logits: 12.8M floats
#define WSWZ_OFF  (PRE_SZ + 12800000)     // bf16 weights: 14*16384 ushort
#define HF_OFF    (PRE_SZ + 13107200)
#define RMAX_OFF  (HF_OFF + B_ * U_)
#define RSUM_OFF  (RMAX_OFF + B_)
// WT (bf16 W_out^T) aliases PRE_OFF — PRE dead after k3; k0b runs after k3.

// PRE per-token layout: [decay(0) | xr(128) | xz(256) | xh(384) | fdir(512) | psi(640)]

typedef float  float4v  __attribute__((ext_vector_type(4)));
typedef short  short8v  __attribute__((ext_vector_type(8)));

// fast transcendentals: v_exp_f32 (2^x) + v_rcp_f32, ~2-3 ULP, branchless.
__device__ __forceinline__ float fsig(float x) {      // 1/(1+e^-x)
    return __builtin_amdgcn_rcpf(1.f + __builtin_amdgcn_exp2f(-1.4426950408889634f * x));
}
__device__ __forceinline__ float ftanh(float x) {     // 1 - 2/(e^{2x}+1)
    return 1.f - 2.f * __builtin_amdgcn_rcpf(1.f + __builtin_amdgcn_exp2f(2.8853900817779268f * x));
}
__device__ __forceinline__ unsigned short f2bf(float f) {   // RNE
    unsigned int u = __float_as_uint(f);
    u = (u + 0x7fffu + ((u >> 16) & 1u)) >> 16;
    return (unsigned short)u;
}
__device__ __forceinline__ unsigned int pack2bf(float a, float b) {
    return (unsigned int)f2bf(a) | ((unsigned int)f2bf(b) << 16);
}
// Barrier draining only LDS (lgkmcnt) — global prefetches stay in flight.
__device__ __forceinline__ void bar_lds() {
    asm volatile("s_waitcnt lgkmcnt(0)\n\ts_barrier" ::: "memory");
}

// ---------------------------------------------------------------------------
// k0: 14 x [128][128] fp32 -> bf16 swizzled  dst[((k>>5)*128 + n)*32 + (k&31)]
// Reading short8 at ((kb*128)+n)*32+q*8 yields S[kb*32+q*8+j][n]:
//   - as B-frag of S (n = output col), or
//   - as A-frag of S^T (n = m row)  — used by k3 for W_h*.
__global__ __launch_bounds__(256) void k0_wconv(
    const float* s0, const float* s1, const float* s2, const float* s3,
    const float* s4, const float* s5, const float* s6, const float* s7,
    const float* s8, const float* s9, const float* s10, const float* s11,
    const float* s12, const float* s13,
    unsigned short* __restrict__ dst)
{
    const float* srcs[14] = { s0,s1,s2,s3,s4,s5,s6,s7,s8,s9,s10,s11,s12,s13 };
    const float* S = srcs[blockIdx.x];
    unsigned short* D = dst + (size_t)blockIdx.x * 16384;
    for (int i = threadIdx.x; i < 16384; i += 256) {
        int k5 = i & 31, n = (i >> 5) & 127, kb = i >> 12;
        D[i] = f2bf(S[(size_t)(kb * 32 + k5) * 128 + n]);
    }
}

// ---------------------------------------------------------------------------
// k0b: W_out [128][50000] fp32 -> WT [n][k] bf16
__global__ __launch_bounds__(256) void k0b_woutT(const float* __restrict__ W_out,
                                                 unsigned short* __restrict__ WT)
{
    int n  = blockIdx.x * 64 + (threadIdx.x >> 2);
    int k0 = (threadIdx.x & 3) * 32;
    if (n >= NC) return;
#pragma unroll 8
    for (int i = 0; i < 32; ++i)
        WT[(size_t)n * 128 + k0 + i] = f2bf(W_out[(size_t)(k0 + i) * NC + n]);
}

// ---------------------------------------------------------------------------
// MFMA helpers (16x16x32 bf16).  A-frag: lane holds A[m0+(lane&15)][kb*32+quad*8+j].
// B-frag (swizzled W): lane holds W[kb*32+quad*8+j][nt*16+(lane&15)].
// C/D: col = lane&15, row = quad*4 + reg.
__device__ __forceinline__ void gemm_k128(const unsigned short (*A)[136],
                                          int m0, int l16, int quad,
                                          const unsigned short* __restrict__ Wm,
                                          float4v acc[8]) {
#pragma unroll
    for (int kb = 0; kb < 4; ++kb) {
        short8v av = *(const short8v*)&A[m0 + l16][kb * 32 + quad * 8];
#pragma unroll
        for (int nt = 0; nt < 8; ++nt) {
            short8v bv = *(const short8v*)(Wm + (((kb * 128) + nt * 16 + l16) * 32 + quad * 8));
            acc[nt] = __builtin_amdgcn_mfma_f32_16x16x32_bf16(av, bv, acc[nt], 0, 0, 0);
        }
    }
}
// A-frags held in registers (gathered directly from the embedding tables).
__device__ __forceinline__ void gemm_reg(const short8v a[4], int l16, int quad,
                                         const unsigned short* __restrict__ Wm,
                                         float4v acc[8]) {
#pragma unroll
    for (int kb = 0; kb < 4; ++kb) {
#pragma unroll
        for (int nt = 0; nt < 8; ++nt) {
            short8v bv = *(const short8v*)(Wm + (((kb * 128) + nt * 16 + l16) * 32 + quad * 8));
            acc[nt] = __builtin_amdgcn_mfma_f32_16x16x32_bf16(a[kb], bv, acc[nt], 0, 0, 0);
        }
    }
}
__device__ __forceinline__ void zero8(float4v acc[8]) {
#pragma unroll
    for (int i = 0; i < 8; ++i) acc[i] = (float4v)0.0f;
}
// 8 contiguous f32 -> one bf16 A-frag word (16B)
__device__ __forceinline__ short8v cvt8(const float* __restrict__ p) {
    float4 v0 = *(const float4*)p;
    float4 v1 = *(const float4*)(p + 4);
    union { unsigned int u[4]; short8v s; } r;
    r.u[0] = pack2bf(v0.x, v0.y);
    r.u[1] = pack2bf(v0.z, v0.w);
    r.u[2] = pack2bf(v1.x, v1.y);
    r.u[3] = pack2bf(v1.z, v1.w);
    return r.s;
}

// ---------------------------------------------------------------------------
// k12: fused MFMA precompute.  grid = NTOK/64, block = 256 (4 waves),
// wave w owns tokens t0+16w .. t0+16w+15.  No barriers (all LDS is wave-local).
__global__ __launch_bounds__(256, 4) void k12_precompute(
    const int* __restrict__ item, const int* __restrict__ tix, const int* __restrict__ frq,
    const float* __restrict__ Ei, const float* __restrict__ Et, const float* __restrict__ Ef,
    const float* __restrict__ b_r, const float* __restrict__ b_z, const float* __restrict__ b_h,
    const float* __restrict__ b_tg, const float* __restrict__ b_fg,
    const float* __restrict__ b_delta, const float* __restrict__ b_f_dir, const float* __restrict__ b_psi,
    const unsigned short* __restrict__ WZ,
    float* __restrict__ PRE)
{
    __shared__ unsigned short Atg[64][136];   // tg (bf16, A-layout)
    __shared__ unsigned short Afg[64][136];   // fg (bf16, A-layout)

    const int t0   = blockIdx.x * 64;
    const int tid  = threadIdx.x;
    const int lane = tid & 63;
    const int wid  = tid >> 6;
    const int quad = lane >> 4;
    const int l16  = lane & 15;
    const int m0   = wid * 16;

    // --- gather embedding rows straight into register A-frags ---
    const int tok = t0 + m0 + l16;
    const int it  = item[tok], tt = tix[tok], ft = frq[tok];
    const float* pei = Ei + (size_t)it * U_ + quad * 8;
    const float* pet = Et + (size_t)tt * U_ + quad * 8;
    const float* pef = Ef + (size_t)ft * U_ + quad * 8;

    short8v axi[4], axt[4], axf[4];
#pragma unroll
    for (int kb = 0; kb < 4; ++kb) axi[kb] = cvt8(pei + kb * 32);
#pragma unroll
    for (int kb = 0; kb < 4; ++kb) axt[kb] = cvt8(pet + kb * 32);
#pragma unroll
    for (int kb = 0; kb < 4; ++kb) axf[kb] = cvt8(pef + kb * 32);

    const unsigned short* WM0  = WZ;                 // W_xtg
    const unsigned short* WM1  = WZ + 1  * 16384;    // W_tg
    const unsigned short* WM2  = WZ + 2  * 16384;    // W_xfg
    const unsigned short* WM3  = WZ + 3  * 16384;    // W_fg
    const unsigned short* WM4  = WZ + 4  * 16384;    // W_xr
    const unsigned short* WM5  = WZ + 5  * 16384;    // W_xz
    const unsigned short* WM6  = WZ + 6  * 16384;    // W_xh
    const unsigned short* WM7  = WZ + 7  * 16384;    // W_delta top (tg rows)
    const unsigned short* WM8  = WZ + 8  * 16384;    // W_delta bot (fg rows)
    const unsigned short* WM9  = WZ + 9  * 16384;    // W_f_dir
    const unsigned short* WM10 = WZ + 10 * 16384;    // W_psi

    float4v acc[8];
    const int tokbase = t0 + m0 + quad * 4;

    // ---- tg = sigmoid(xi@W_xtg + xt@W_tg + b_tg) -> Atg (bf16, A-layout) ----
    zero8(acc);
    gemm_reg(axi, l16, quad, WM0, acc);
    gemm_reg(axt, l16, quad, WM1, acc);
#pragma unroll
    for (int nt = 0; nt < 8; ++nt) {
        int n = nt * 16 + l16;
        float bb = b_tg[n];
#pragma unroll
        for (int r = 0; r < 4; ++r)
            Atg[m0 + quad * 4 + r][n] = f2bf(fsig(acc[nt][r] + bb));
    }
    // ---- fg = sigmoid(xi@W_xfg + xf@W_fg + b_fg) -> Afg ----
    zero8(acc);
    gemm_reg(axi, l16, quad, WM2, acc);
    gemm_reg(axf, l16, quad, WM3, acc);
#pragma unroll
    for (int nt = 0; nt < 8; ++nt) {
        int n = nt * 16 + l16;
        float bb = b_fg[n];
#pragma unroll
        for (int r = 0; r < 4; ++r)
            Afg[m0 + quad * 4 + r][n] = f2bf(fsig(acc[nt][r] + bb));
    }

    // ---- xr, xz, xh (xi only — hides the Atg/Afg LDS write->read latency) ----
    {
        const unsigned short* Wx[3] = { WM4, WM5, WM6 };
        const float* bx[3] = { b_r, b_z, b_h };
        const int    off[3] = { 128, 256, 384 };
#pragma unroll
        for (int m = 0; m < 3; ++m) {
            zero8(acc);
            gemm_reg(axi, l16, quad, Wx[m], acc);
#pragma unroll
            for (int nt = 0; nt < 8; ++nt) {
                int n = nt * 16 + l16;
                float bb = bx[m][n];
#pragma unroll
                for (int r = 0; r < 4; ++r)
                    PRE[(size_t)(tokbase + r) * 768 + off[m] + n] = acc[nt][r] + bb;
            }
        }
    }
    // ---- decay = exp(-softplus(y)) == sigmoid(-y), y = [tg|fg]@W_delta + b ----
    zero8(acc);
    gemm_k128(Atg, m0, l16, quad, WM7, acc);
    gemm_k128(Afg, m0, l16, quad, WM8, acc);
#pragma unroll
    for (int nt = 0; nt < 8; ++nt) {
        int n = nt * 16 + l16;
        float bb = b_delta[n];
#pragma unroll
        for (int r = 0; r < 4; ++r)
            PRE[(size_t)(tokbase + r) * 768 + 0 + n] = fsig(-(acc[nt][r] + bb));
    }
    // ---- fdir = fg@W_f_dir + b ----
    zero8(acc);
    gemm_k128(Afg, m0, l16, quad, WM9, acc);
#pragma unroll
    for (int nt = 0; nt < 8; ++nt) {
        int n = nt * 16 + l16;
        float bb = b_f_dir[n];
#pragma unroll
        for (int r = 0; r < 4; ++r)
            PRE[(size_t)(tokbase + r) * 768 + 512 + n] = acc[nt][r] + bb;
    }
    // ---- psi = sigmoid(fg@W_psi + b) ----
    zero8(acc);
    gemm_k128(Afg, m0, l16, quad, WM10, acc);
#pragma unroll
    for (int nt = 0; nt < 8; ++nt) {
        int n = nt * 16 + l16;
        float bb = b_psi[n];
#pragma unroll
        for (int r = 0; r < 4; ++r)
            PRE[(size_t)(tokbase + r) * 768 + 640 + n] = fsig(acc[nt][r] + bb);
    }
}

// ---------------------------------------------------------------------------
// k3: MFMA recurrence.  16 wgs x 16 batch rows; 256 thr = 4 waves.
//   GEMM form: C[m=dim][n=batch] = Wh^T @ Hd^T via mfma_16x16x32_bf16.
//   A = W^T A-frags (from k0 swizzle slots 11-13), loop-invariant, pinned.
//   B = state B-frags from LDS  StB[batch][dim] bf16, XOR-swizzled
//       (byte ^= (row&7)<<4) to break the 16-row bank aliasing.
//   C layout: lane&15 = batch, quad*4+reg = dim  ->  ALL gating elementwise
//   ops are lane-local; fp32 master state hd32 lives in C-layout registers.
//   Per step: P1 r,z GEMMs -> rh,z; write RhB; bar; P2 h GEMM -> update;
//   write HdB; bar.  PRE constants prefetched 1 step ahead (in-place).
__global__ __launch_bounds__(256, 1) void k3_scan(
    const float* __restrict__ PRE,
    const unsigned short* __restrict__ WZ,
    unsigned short* __restrict__ Hb)
{
    const int b0   = blockIdx.x * 16;
    const int tid  = threadIdx.x;
    const int lane = tid & 63;
    const int wid  = tid >> 6;      // 0..3
    const int q    = lane >> 4;     // 0..3
    const int l16  = lane & 15;     // batch within group
    const int swz  = (l16 & 7) << 4;

    __shared__ __align__(16) unsigned short HdB[16][136];
    __shared__ __align__(16) unsigned short RhB[16][136];
    for (int i = tid; i < 16 * 136; i += 256) ((unsigned short*)HdB)[i] = 0;

    // ---- loop-invariant A-frags of W_hr^T / W_hz^T / W_hh^T (pinned) ----
    int4 arI[2][4], azI[2][4], ahI[2][4];
    {
        const unsigned short* WZr = WZ + 11 * 16384;
        const unsigned short* WZz = WZ + 12 * 16384;
        const unsigned short* WZh = WZ + 13 * 16384;
#pragma unroll
        for (int t = 0; t < 2; ++t)
#pragma unroll
            for (int kb = 0; kb < 4; ++kb) {
                int idx = ((kb * 128) + (2 * wid + t) * 16 + l16) * 32 + q * 8;
                arI[t][kb] = *(const int4*)(WZr + idx);
                azI[t][kb] = *(const int4*)(WZz + idx);
                ahI[t][kb] = *(const int4*)(WZh + idx);
            }
#pragma unroll
        for (int t = 0; t < 2; ++t)
#pragma unroll
            for (int kb = 0; kb < 4; ++kb) {
                asm volatile("" : "+v"(arI[t][kb].x), "+v"(arI[t][kb].y),
                                  "+v"(arI[t][kb].z), "+v"(arI[t][kb].w));
                asm volatile("" : "+v"(azI[t][kb].x), "+v"(azI[t][kb].y),
                                  "+v"(azI[t][kb].z), "+v"(azI[t][kb].w));
                asm volatile("" : "+v"(ahI[t][kb].x), "+v"(ahI[t][kb].y),
                                  "+v"(ahI[t][kb].z), "+v"(ahI[t][kb].w));
            }
    }
#define AFR(t,kb) (*(const short8v*)&arI[t][kb])
#define AFZ(t,kb) (*(const short8v*)&azI[t][kb])
#define AFH(t,kb) (*(const short8v*)&ahI[t][kb])

    // ---- PRE constants for this lane's (batch l16, dims 16tt+4q+0..3) ----
    const float* pb = PRE + (size_t)(b0 + l16) * (S_ * 768);
    const int d4[2] = { 16 * (2 * wid + 0) + 4 * q, 16 * (2 * wid + 1) + 4 * q };

    float4 cxr[2], cxz[2], cxh[2], cfd[2], cps[2], cdk[2];
#pragma unroll
    for (int t = 0; t < 2; ++t) {
        cxr[t] = *(const float4*)(pb + 128 + d4[t]);
        cxz[t] = *(const float4*)(pb + 256 + d4[t]);
        cxh[t] = *(const float4*)(pb + 384 + d4[t]);
        cfd[t] = *(const float4*)(pb + 512 + d4[t]);
        cps[t] = *(const float4*)(pb + 640 + d4[t]);
        cdk[t] = *(const float4*)(pb + 768 + d4[t]);   // decay[1]
    }

    float4 hd32[2];
    hd32[0] = make_float4(0.f, 0.f, 0.f, 0.f);
    hd32[1] = make_float4(0.f, 0.f, 0.f, 0.f);
    float4 zv[2];
    bar_lds();

    for (int s = 0; s < S_; ++s) {
        const float* pn = pb + (size_t)(s + 1) * 768;

        // ---- P1: r,z GEMMs over Hd ----
        float4v accr[2] = { (float4v)0.f, (float4v)0.f };
        float4v accz[2] = { (float4v)0.f, (float4v)0.f };
#pragma unroll
        for (int kb = 0; kb < 4; ++kb) {
            int co = (64 * kb + 16 * q) ^ swz;
            short8v bh = *(const short8v*)((const char*)&HdB[l16][0] + co);
#pragma unroll
            for (int t = 0; t < 2; ++t) {
                accr[t] = __builtin_amdgcn_mfma_f32_16x16x32_bf16(AFR(t,kb), bh, accr[t], 0, 0, 0);
                accz[t] = __builtin_amdgcn_mfma_f32_16x16x32_bf16(AFZ(t,kb), bh, accz[t], 0, 0, 0);
            }
        }
#pragma unroll
        for (int t = 0; t < 2; ++t) {
            float r0 = fsig(cxr[t].x + accr[t][0]) * hd32[t].x;
            float r1 = fsig(cxr[t].y + accr[t][1]) * hd32[t].y;
            float r2 = fsig(cxr[t].z + accr[t][2]) * hd32[t].z;
            float r3 = fsig(cxr[t].w + accr[t][3]) * hd32[t].w;
            zv[t].x = fsig(cxz[t].x + accz[t][0]);
            zv[t].y = fsig(cxz[t].y + accz[t][1]);
            zv[t].z = fsig(cxz[t].z + accz[t][2]);
            zv[t].w = fsig(cxz[t].w + accz[t][3]);
            uint2 w; w.x = pack2bf(r0, r1); w.y = pack2bf(r2, r3);
            int co = (2 * d4[t]) ^ swz;
            *(uint2*)((char*)&RhB[l16][0] + co) = w;
        }
        // prefetch next-step xr,xz (in-place; consumed next P1 epilogue)
#pragma unroll
        for (int t = 0; t < 2; ++t) {
            cxr[t] = *(const float4*)(pn + 128 + d4[t]);
            cxz[t] = *(const float4*)(pn + 256 + d4[t]);
        }
        bar_lds();   // RhB ready

        // ---- P2: h GEMM over Rh ----
        float4v acch[2] = { (float4v)0.f, (float4v)0.f };
#pragma unroll
        for (int kb = 0; kb < 4; ++kb) {
            int co = (64 * kb + 16 * q) ^ swz;
            short8v br = *(const short8v*)((const char*)&RhB[l16][0] + co);
#pragma unroll
            for (int t = 0; t < 2; ++t)
                acch[t] = __builtin_amdgcn_mfma_f32_16x16x32_bf16(AFH(t,kb), br, acch[t], 0, 0, 0);
        }
#pragma unroll
        for (int t = 0; t < 2; ++t) {
            float hb0 = ftanh(cxh[t].x + acch[t][0]);
            float hb1 = ftanh(cxh[t].y + acch[t][1]);
            float hb2 = ftanh(cxh[t].z + acch[t][2]);
            float hb3 = ftanh(cxh[t].w + acch[t][3]);
            float hf0 = ftanh(hb0 + cfd[t].x), hf1 = ftanh(hb1 + cfd[t].y);
            float hf2 = ftanh(hb2 + cfd[t].z), hf3 = ftanh(hb3 + cfd[t].w);
            float hc0 = (1.f - cps[t].x) * hb0 + cps[t].x * hf0;
            float hc1 = (1.f - cps[t].y) * hb1 + cps[t].y * hf1;
            float hc2 = (1.f - cps[t].z) * hb2 + cps[t].z * hf2;
            float hc3 = (1.f - cps[t].w) * hb3 + cps[t].w * hf3;
            float hn0 = (1.f - zv[t].x) * hd32[t].x + zv[t].x * hc0;
            float hn1 = (1.f - zv[t].y) * hd32[t].y + zv[t].y * hc1;
            float hn2 = (1.f - zv[t].z) * hd32[t].z + zv[t].z * hc2;
            float hn3 = (1.f - zv[t].w) * hd32[t].w + zv[t].w * hc3;
            hd32[t].x = cdk[t].x * hn0; hd32[t].y = cdk[t].y * hn1;
            hd32[t].z = cdk[t].z * hn2; hd32[t].w = cdk[t].w * hn3;
            uint2 w; w.x = pack2bf(hd32[t].x, hd32[t].y); w.y = pack2bf(hd32[t].z, hd32[t].w);
            int co = (2 * d4[t]) ^ swz;
            *(uint2*)((char*)&HdB[l16][0] + co) = w;
            if (s == S_ - 1) {
                uint2 o; o.x = pack2bf(hn0, hn1); o.y = pack2bf(hn2, hn3);
                *(uint2*)&Hb[(size_t)(b0 + l16) * U_ + d4[t]] = o;
            }
        }
        // prefetch next-step xh,fd,ps,dk (in-place; consumed next P2 epilogue)
#pragma unroll
        for (int t = 0; t < 2; ++t) {
            cxh[t] = *(const float4*)(pn + 384 + d4[t]);
            cfd[t] = *(const float4*)(pn + 512 + d4[t]);
            cps[t] = *(const float4*)(pn + 640 + d4[t]);
            cdk[t] = *(const float4*)(pn + 768 + d4[t]);   // decay[s+2]
        }
        bar_lds();   // HdB ready for next step
    }
#undef AFR
#undef AFZ
#undef AFH
}

// ---------------------------------------------------------------------------
// k4a: logits = h @ W_out + b_out via bf16 MFMA.
__global__ __launch_bounds__(256) void k4a_logits(
    const unsigned short* __restrict__ Hb, const unsigned short* __restrict__ WT,
    const float* __restrict__ b_out, float* __restrict__ logits)
{
    const int tid  = threadIdx.x;
    const int lane = tid & 63, wid = tid >> 6;
    const int quad = lane >> 4, l16 = lane & 15;
    const int rb = blockIdx.y * 64 + wid * 16;
    const int cb = blockIdx.x * 128;

    short8v av[4];
#pragma unroll
    for (int kb = 0; kb < 4; ++kb)
        av[kb] = *(const short8v*)&Hb[(size_t)(rb + l16) * 128 + kb * 32 + quad * 8];

    float4v acc[8];
#pragma unroll
    for (int i = 0; i < 8; ++i) acc[i] = (float4v)0.0f;

#pragma unroll
    for (int kb = 0; kb < 4; ++kb) {
#pragma unroll
        for (int nt = 0; nt < 8; ++nt) {
            short8v bv = *(const short8v*)&WT[(size_t)(cb + nt * 16 + l16) * 128 + kb * 32 + quad * 8];
            acc[nt] = __builtin_amdgcn_mfma_f32_16x16x32_bf16(av[kb], bv, acc[nt], 0, 0, 0);
        }
    }
#pragma unroll
    for (int nt = 0; nt < 8; ++nt) {
        int n = cb + nt * 16 + l16;
        if (n < NC) {
            float bb = b_out[n];
#pragma unroll
            for (int r = 0; r < 4; ++r)
                logits[(size_t)(rb + quad * 4 + r) * NC + n] = acc[nt][r] + bb;
        }
    }
}

// ---------------------------------------------------------------------------
__global__ __launch_bounds__(256) void k4b_rowstats(
    const float* __restrict__ logits, float* __restrict__ rmax, float* __restrict__ rsum)
{
    const int r = blockIdx.x;
    const int tid = threadIdx.x;
    const float* row = logits + (size_t)r * NC;

    float m = -INFINITY, s = 0.f;
    for (int c = tid; c < NC; c += 256) {
        float x = row[c];
        float mn = fmaxf(m, x);
        s = s * expf(m - mn) + expf(x - mn);
        m = mn;
    }
    __shared__ float sm[256], ss[256];
    sm[tid] = m; ss[tid] = s;
    __syncthreads();
    for (int off = 128; off > 0; off >>= 1) {
        if (tid < off) {
            float m2 = sm[tid + off], s2 = ss[tid + off];
            float M = fmaxf(sm[tid], m2);
            ss[tid] = ss[tid] * expf(sm[tid] - M) + s2 * expf(m2 - M);
            sm[tid] = M;
        }
        __syncthreads();
    }
    if (tid == 0) { rmax[r] = sm[0]; rsum[r] = ss[0]; }
}

__global__ __launch_bounds__(256) void k4c_norm(
    const float* __restrict__ logits, const float* __restrict__ rmax,
    const float* __restrict__ rsum, float* __restrict__ out)
{
    const int r = blockIdx.y;
    const int c = blockIdx.x * 256 + threadIdx.x;
    if (c < NC) {
        size_t i = (size_t)r * NC + c;
        out[i] = expf(logits[i] - rmax[r]) / rsum[r];
    }
}

// ---------------------------------------------------------------------------
extern "C" void kernel_launch(void* const* d_in, const int* in_sizes, int n_in,
                              void* d_out, int out_size, void* d_ws, size_t ws_size,
                              hipStream_t stream) {
    const int*   item   = (const int*)d_in[0];
    const int*   tix    = (const int*)d_in[1];
    const int*   frq    = (const int*)d_in[2];
    const float* Ei     = (const float*)d_in[3];
    const float* Et     = (const float*)d_in[4];
    const float* Ef     = (const float*)d_in[5];
    const float* W_xr   = (const float*)d_in[6];
    const float* W_hr   = (const float*)d_in[7];
    const float* b_r    = (const float*)d_in[8];
    const float* W_xz   = (const float*)d_in[9];
    const float* W_hz   = (const float*)d_in[10];
    const float* b_z    = (const float*)d_in[11];
    const float* W_xh   = (const float*)d_in[12];
    const float* W_hh   = (const float*)d_in[13];
    const float* b_h    = (const float*)d_in[14];
    const float* W_xtg  = (const float*)d_in[15];
    const float* W_tg   = (const float*)d_in[16];
    const float* b_tg   = (const float*)d_in[17];
    const float* W_xfg  = (const float*)d_in[18];
    const float* W_fg   = (const float*)d_in[19];
    const float* b_fg   = (const float*)d_in[20];
    const float* W_delta= (const float*)d_in[21];
    const float* b_delta= (const float*)d_in[22];
    const float* W_f_dir= (const float*)d_in[23];
    const float* b_f_dir= (const float*)d_in[24];
    const float* W_psi  = (const float*)d_in[25];
    const float* b_psi  = (const float*)d_in[26];
    // d_in[27] = W_a — dead (softmax over singleton axis == 1)
    const float* W_out  = (const float*)d_in[28];
    const float* b_out  = (const float*)d_in[29];
    float* out = (float*)d_out;

    float* ws   = (float*)d_ws;
    float* PRE  = ws + PRE_OFF;
    float* LOG  = ws + LOG_OFF;
    unsigned short* WSWZ = (unsigned short*)(ws + WSWZ_OFF);
    unsigned short* WT   = (unsigned short*)(ws + PRE_OFF);   // aliases PRE (dead after k3)
    unsigned short* Hb   = (unsigned short*)(ws + HF_OFF);
    float* RMAX = ws + RMAX_OFF;
    float* RSUM = ws + RSUM_OFF;

    k0_wconv<<<14, 256, 0, stream>>>(
        W_xtg, W_tg, W_xfg, W_fg, W_xr, W_xz, W_xh,
        W_delta, W_delta + 128 * 128, W_f_dir, W_psi,
        W_hr, W_hz, W_hh, WSWZ);
    k12_precompute<<<NTOK / 64, 256, 0, stream>>>(
        item, tix, frq, Ei, Et, Ef,
        b_r, b_z, b_h, b_tg, b_fg, b_delta, b_f_dir, b_psi,
        WSWZ, PRE);
    k3_scan<<<16, 256, 0, stream>>>(PRE, WSWZ, Hb);
    k0b_woutT<<<(NC + 63) / 64, 256, 0, stream>>>(W_out, WT);
    k4a_logits<<<dim3((NC + 127) / 128, B_ / 64), 256, 0, stream>>>(Hb, WT, b_out, LOG);
    k4b_rowstats<<<B_, 256, 0, stream>>>(LOG, RMAX, RSUM);
    k4c_norm<<<dim3((NC + 255) / 256, B_), 256, 0, stream>>>(LOG, RMAX, RSUM, out);
}

// Round 6
// 616.840 us; speedup vs baseline: 1.2737x; 1.2737x over previous
//
#include <hip/hip_runtime.h>
#include <math.h>

// ---------------------------------------------------------------------------
// LongRec.  B=256, S=200, D=U=128, NC=50000.
// alpha = softmax over singleton axis == 1.0 -> h_att = h_d; W_a is dead.
// Pipeline:
//   k0  : 12 x [128][128] weights fp32 -> bf16 k-swizzled for MFMA B-frags
//   k12 : MFMA precompute -> PRE **bf16** (reg A-frag gather; fast sigmoid;
//         decay = exp(-softplus(y)) == sigmoid(-y)).  bf16 PRE halves the
//         write traffic (R1 showed k12 write-BW heavy: 154MB @ 820GB/s).
//   k3  : 200-step recurrence, 1 wg/row, 512 thr = 8 waves (R3 structure —
//         R5's 16-wg MFMA form was per-CU-BW-bound on constants, reverted).
//         R11: k-group moved to the quad (kg=lane&3) so the reduction is two
//         quad_perm DPP VALU ops (was 2 LDS-pipe shfl_xor ~120cy); 4-way
//         accumulator split (8-deep FMA chains, was 32); bf16 PRE loads.
//         2 lgkm-only barriers/step; rolling prefetch in vmcnt flight.
//   k0b : W_out -> bf16 WT[n][k]  (aliases PRE, dead after k3)
//   k4a : logits = h @ W_out + b_out via bf16 MFMA
//   k4b/c: row stats, softmax normalize
// ---------------------------------------------------------------------------

#define B_  256
#define S_  200
#define U_  128
#define NC  50000
#define NTOK (B_ * S_)       // 51200

// ws layout (in floats).  PRE is bf16 now: NTOK*768 ushorts = 19.66M floats.
#define PRE_OFF   0
#define PRE_FL    (NTOK * 768 / 2)        // 19660800 floats
#define LOG_OFF   PRE_FL                  // logits: 12.8M floats
#define WSWZ_OFF  (LOG_OFF + 12800000)    // bf16 weights: 12*16384 ushort
#define HF_OFF    (WSWZ_OFF + 98304)      // Hb: B_*U_ ushorts (pad to floats)
#define RMAX_OFF  (HF_OFF + B_ * U_ / 2)
#define RSUM_OFF  (RMAX_OFF + B_)
// WT (bf16 W_out^T, 3.2M floats) aliases PRE_OFF — PRE dead after k3.

// PRE per-token layout (ushort idx): [decay(0)|xr(128)|xz(256)|xh(384)|fdir(512)|psi(640)]

typedef float  float4v  __attribute__((ext_vector_type(4)));
typedef short  short8v  __attribute__((ext_vector_type(8)));

// fast transcendentals: v_exp_f32 (2^x) + v_rcp_f32, ~2-3 ULP, branchless.
__device__ __forceinline__ float fsig(float x) {      // 1/(1+e^-x)
    return __builtin_amdgcn_rcpf(1.f + __builtin_amdgcn_exp2f(-1.4426950408889634f * x));
}
__device__ __forceinline__ float ftanh(float x) {     // 1 - 2/(e^{2x}+1)
    return 1.f - 2.f * __builtin_amdgcn_rcpf(1.f + __builtin_amdgcn_exp2f(2.8853900817779268f * x));
}
__device__ __forceinline__ unsigned short f2bf(float f) {   // RNE
    unsigned int u = __float_as_uint(f);
    u = (u + 0x7fffu + ((u >> 16) & 1u)) >> 16;
    return (unsigned short)u;
}
__device__ __forceinline__ unsigned int pack2bf(float a, float b) {
    return (unsigned int)f2bf(a) | ((unsigned int)f2bf(b) << 16);
}
__device__ __forceinline__ float bf2f(unsigned short u) {
    return __uint_as_float((unsigned int)u << 16);
}
// Barrier draining only LDS (lgkmcnt) — global prefetches stay in flight.
__device__ __forceinline__ void bar_lds() {
    asm volatile("s_waitcnt lgkmcnt(0)\n\ts_barrier" ::: "memory");
}
// VALU cross-lane add via DPP quad_perm: 0xB1 = xor1, 0x4E = xor2.
template<int CTRL>
__device__ __forceinline__ float dppadd(float x) {
    return x + __int_as_float(
        __builtin_amdgcn_mov_dpp(__float_as_int(x), CTRL, 0xF, 0xF, true));
}

// ---------------------------------------------------------------------------
// k0: 12 x [128][128] fp32 -> bf16 swizzled  dst[((k>>5)*128 + n)*32 + (k&31)]
__global__ __launch_bounds__(256) void k0_wconv(
    const float* s0, const float* s1, const float* s2, const float* s3,
    const float* s4, const float* s5, const float* s6, const float* s7,
    const float* s8, const float* s9, const float* s10, const float* s11,
    unsigned short* __restrict__ dst)
{
    const float* srcs[12] = { s0,s1,s2,s3,s4,s5,s6,s7,s8,s9,s10,s11 };
    const float* S = srcs[blockIdx.x];
    unsigned short* D = dst + (size_t)blockIdx.x * 16384;
    for (int i = threadIdx.x; i < 16384; i += 256) {
        int k5 = i & 31, n = (i >> 5) & 127, kb = i >> 12;
        D[i] = f2bf(S[(size_t)(kb * 32 + k5) * 128 + n]);
    }
}

// ---------------------------------------------------------------------------
// k0b: W_out [128][50000] fp32 -> WT [n][k] bf16
__global__ __launch_bounds__(256) void k0b_woutT(const float* __restrict__ W_out,
                                                 unsigned short* __restrict__ WT)
{
    int n  = blockIdx.x * 64 + (threadIdx.x >> 2);
    int k0 = (threadIdx.x & 3) * 32;
    if (n >= NC) return;
#pragma unroll 8
    for (int i = 0; i < 32; ++i)
        WT[(size_t)n * 128 + k0 + i] = f2bf(W_out[(size_t)(k0 + i) * NC + n]);
}

// ---------------------------------------------------------------------------
// MFMA helpers (16x16x32 bf16).  A-frag: lane holds A[m0+(lane&15)][kb*32+quad*8+j].
// B-frag (swizzled W): lane holds W[kb*32+quad*8+j][nt*16+(lane&15)].
// C/D: col = lane&15, row = quad*4 + reg.
__device__ __forceinline__ void gemm_k128(const unsigned short (*A)[136],
                                          int m0, int l16, int quad,
                                          const unsigned short* __restrict__ Wm,
                                          float4v acc[8]) {
#pragma unroll
    for (int kb = 0; kb < 4; ++kb) {
        short8v av = *(const short8v*)&A[m0 + l16][kb * 32 + quad * 8];
#pragma unroll
        for (int nt = 0; nt < 8; ++nt) {
            short8v bv = *(const short8v*)(Wm + (((kb * 128) + nt * 16 + l16) * 32 + quad * 8));
            acc[nt] = __builtin_amdgcn_mfma_f32_16x16x32_bf16(av, bv, acc[nt], 0, 0, 0);
        }
    }
}
// A-frags held in registers (gathered directly from the embedding tables).
__device__ __forceinline__ void gemm_reg(const short8v a[4], int l16, int quad,
                                         const unsigned short* __restrict__ Wm,
                                         float4v acc[8]) {
#pragma unroll
    for (int kb = 0; kb < 4; ++kb) {
#pragma unroll
        for (int nt = 0; nt < 8; ++nt) {
            short8v bv = *(const short8v*)(Wm + (((kb * 128) + nt * 16 + l16) * 32 + quad * 8));
            acc[nt] = __builtin_amdgcn_mfma_f32_16x16x32_bf16(a[kb], bv, acc[nt], 0, 0, 0);
        }
    }
}
__device__ __forceinline__ void zero8(float4v acc[8]) {
#pragma unroll
    for (int i = 0; i < 8; ++i) acc[i] = (float4v)0.0f;
}
// 8 contiguous f32 -> one bf16 A-frag word (16B)
__device__ __forceinline__ short8v cvt8(const float* __restrict__ p) {
    float4 v0 = *(const float4*)p;
    float4 v1 = *(const float4*)(p + 4);
    union { unsigned int u[4]; short8v s; } r;
    r.u[0] = pack2bf(v0.x, v0.y);
    r.u[1] = pack2bf(v0.z, v0.w);
    r.u[2] = pack2bf(v1.x, v1.y);
    r.u[3] = pack2bf(v1.z, v1.w);
    return r.s;
}

// ---------------------------------------------------------------------------
// k12: fused MFMA precompute.  grid = NTOK/64, block = 256 (4 waves),
// wave w owns tokens t0+16w .. t0+16w+15.  No barriers (all LDS is wave-local).
// PRE written as bf16 (halves the dominant write traffic).
__global__ __launch_bounds__(256, 4) void k12_precompute(
    const int* __restrict__ item, const int* __restrict__ tix, const int* __restrict__ frq,
    const float* __restrict__ Ei, const float* __restrict__ Et, const float* __restrict__ Ef,
    const float* __restrict__ b_r, const float* __restrict__ b_z, const float* __restrict__ b_h,
    const float* __restrict__ b_tg, const float* __restrict__ b_fg,
    const float* __restrict__ b_delta, const float* __restrict__ b_f_dir, const float* __restrict__ b_psi,
    const unsigned short* __restrict__ WZ,
    unsigned short* __restrict__ PRE)
{
    __shared__ unsigned short Atg[64][136];   // tg (bf16, A-layout)
    __shared__ unsigned short Afg[64][136];   // fg (bf16, A-layout)

    const int t0   = blockIdx.x * 64;
    const int tid  = threadIdx.x;
    const int lane = tid & 63;
    const int wid  = tid >> 6;
    const int quad = lane >> 4;
    const int l16  = lane & 15;
    const int m0   = wid * 16;

    // --- gather embedding rows straight into register A-frags ---
    const int tok = t0 + m0 + l16;
    const int it  = item[tok], tt = tix[tok], ft = frq[tok];
    const float* pei = Ei + (size_t)it * U_ + quad * 8;
    const float* pet = Et + (size_t)tt * U_ + quad * 8;
    const float* pef = Ef + (size_t)ft * U_ + quad * 8;

    short8v axi[4], axt[4], axf[4];
#pragma unroll
    for (int kb = 0; kb < 4; ++kb) axi[kb] = cvt8(pei + kb * 32);
#pragma unroll
    for (int kb = 0; kb < 4; ++kb) axt[kb] = cvt8(pet + kb * 32);
#pragma unroll
    for (int kb = 0; kb < 4; ++kb) axf[kb] = cvt8(pef + kb * 32);

    const unsigned short* WM0  = WZ;                 // W_xtg
    const unsigned short* WM1  = WZ + 1  * 16384;    // W_tg
    const unsigned short* WM2  = WZ + 2  * 16384;    // W_xfg
    const unsigned short* WM3  = WZ + 3  * 16384;    // W_fg
    const unsigned short* WM4  = WZ + 4  * 16384;    // W_xr
    const unsigned short* WM5  = WZ + 5  * 16384;    // W_xz
    const unsigned short* WM6  = WZ + 6  * 16384;    // W_xh
    const unsigned short* WM7  = WZ + 7  * 16384;    // W_delta top (tg rows)
    const unsigned short* WM8  = WZ + 8  * 16384;    // W_delta bot (fg rows)
    const unsigned short* WM9  = WZ + 9  * 16384;    // W_f_dir
    const unsigned short* WM10 = WZ + 10 * 16384;    // W_psi

    float4v acc[8];
    const int tokbase = t0 + m0 + quad * 4;

    // ---- tg = sigmoid(xi@W_xtg + xt@W_tg + b_tg) -> Atg (bf16, A-layout) ----
    zero8(acc);
    gemm_reg(axi, l16, quad, WM0, acc);
    gemm_reg(axt, l16, quad, WM1, acc);
#pragma unroll
    for (int nt = 0; nt < 8; ++nt) {
        int n = nt * 16 + l16;
        float bb = b_tg[n];
#pragma unroll
        for (int r = 0; r < 4; ++r)
            Atg[m0 + quad * 4 + r][n] = f2bf(fsig(acc[nt][r] + bb));
    }
    // ---- fg = sigmoid(xi@W_xfg + xf@W_fg + b_fg) -> Afg ----
    zero8(acc);
    gemm_reg(axi, l16, quad, WM2, acc);
    gemm_reg(axf, l16, quad, WM3, acc);
#pragma unroll
    for (int nt = 0; nt < 8; ++nt) {
        int n = nt * 16 + l16;
        float bb = b_fg[n];
#pragma unroll
        for (int r = 0; r < 4; ++r)
            Afg[m0 + quad * 4 + r][n] = f2bf(fsig(acc[nt][r] + bb));
    }

    // ---- xr, xz, xh (xi only — hides the Atg/Afg LDS write->read latency) ----
    {
        const unsigned short* Wx[3] = { WM4, WM5, WM6 };
        const float* bx[3] = { b_r, b_z, b_h };
        const int    off[3] = { 128, 256, 384 };
#pragma unroll
        for (int m = 0; m < 3; ++m) {
            zero8(acc);
            gemm_reg(axi, l16, quad, Wx[m], acc);
#pragma unroll
            for (int nt = 0; nt < 8; ++nt) {
                int n = nt * 16 + l16;
                float bb = bx[m][n];
#pragma unroll
                for (int r = 0; r < 4; ++r)
                    PRE[(size_t)(tokbase + r) * 768 + off[m] + n] = f2bf(acc[nt][r] + bb);
            }
        }
    }
    // ---- decay = exp(-softplus(y)) == sigmoid(-y), y = [tg|fg]@W_delta + b ----
    zero8(acc);
    gemm_k128(Atg, m0, l16, quad, WM7, acc);
    gemm_k128(Afg, m0, l16, quad, WM8, acc);
#pragma unroll
    for (int nt = 0; nt < 8; ++nt) {
        int n = nt * 16 + l16;
        float bb = b_delta[n];
#pragma unroll
        for (int r = 0; r < 4; ++r)
            PRE[(size_t)(tokbase + r) * 768 + 0 + n] = f2bf(fsig(-(acc[nt][r] + bb)));
    }
    // ---- fdir = fg@W_f_dir + b ----
    zero8(acc);
    gemm_k128(Afg, m0, l16, quad, WM9, acc);
#pragma unroll
    for (int nt = 0; nt < 8; ++nt) {
        int n = nt * 16 + l16;
        float bb = b_f_dir[n];
#pragma unroll
        for (int r = 0; r < 4; ++r)
            PRE[(size_t)(tokbase + r) * 768 + 512 + n] = f2bf(acc[nt][r] + bb);
    }
    // ---- psi = sigmoid(fg@W_psi + b) ----
    zero8(acc);
    gemm_k128(Afg, m0, l16, quad, WM10, acc);
#pragma unroll
    for (int nt = 0; nt < 8; ++nt) {
        int n = nt * 16 + l16;
        float bb = b_psi[n];
#pragma unroll
        for (int r = 0; r < 4; ++r)
            PRE[(size_t)(tokbase + r) * 768 + 640 + n] = f2bf(fsig(acc[nt][r] + bb));
    }
}

// ---------------------------------------------------------------------------
// k3: one workgroup per batch row; 512 threads = 8 waves (R3 structure).
//   k-group = quad lane (kg = lane&3): lane owns k in {16q + 4kg + j}, q<8,
//   j<4 (32 k), accumulated into 4 independent accs (8-deep FMA chains).
//   Reduction = 2 quad_perm DPP adds (pure VALU, ~20cy — was 2 LDS-pipe
//   shuffles ~120cy).  hd reads are 4-address 16-lane broadcasts (no
//   conflicts).  P1: waves 0-3 r (2 cols each via colA), waves 4-7 z.
//   P2: all 8 waves h-matvec (1 col via colB) + update in-register.
//   2 lgkm-only barriers/step; bf16 PRE constants prefetched 1 step ahead
//   (rolling pointers, stay in vmcnt flight across barriers).
__global__ __launch_bounds__(512, 2) void k3_scan(
    const unsigned short* __restrict__ PRE,
    const float* __restrict__ W_hr, const float* __restrict__ W_hz, const float* __restrict__ W_hh,
    unsigned short* __restrict__ Hb)
{
    const int b    = blockIdx.x;
    const int tid  = threadIdx.x;
    const int lane = tid & 63;
    const int wid  = tid >> 6;          // 0..7
    const int cp   = lane >> 2;         // 0..15 (col selector)
    const int kg   = lane & 3;          // 0..3  (k-group = quad lane)

    const int colA = ((wid & 3) << 5) + (cp << 1);   // P1: 2 cols (even)
    const int colB = (wid << 4) + cp;                // P2: 1 col

    // --- loop-invariant weights pinned in VGPRs ---
    const float* Wrz = (wid < 4) ? W_hr : W_hz;
    float wrz[64];   // [(q*4+j)*2+c] = Wrz[16q+4kg+j][colA+c]
#pragma unroll
    for (int q = 0; q < 8; ++q)
#pragma unroll
        for (int j = 0; j < 4; ++j) {
            float2 wv = *(const float2*)&Wrz[(size_t)(16 * q + 4 * kg + j) * U_ + colA];
            wrz[(q * 4 + j) * 2 + 0] = wv.x;
            wrz[(q * 4 + j) * 2 + 1] = wv.y;
        }
    float whh[32];   // [q*4+j] = W_hh[16q+4kg+j][colB]
#pragma unroll
    for (int q = 0; q < 8; ++q)
#pragma unroll
        for (int j = 0; j < 4; ++j)
            whh[q * 4 + j] = W_hh[(size_t)(16 * q + 4 * kg + j) * U_ + colB];
#pragma unroll
    for (int k = 0; k < 64; ++k) asm volatile("" : "+v"(wrz[k]));
#pragma unroll
    for (int k = 0; k < 32; ++k) asm volatile("" : "+v"(whh[k]));

    __shared__ __align__(16) float hd[U_];
    __shared__ __align__(16) float rh[U_];
    __shared__ __align__(16) float zb[U_];
    if (tid < U_) hd[tid] = 0.f;    // h0 = 0 -> h_d(step 0) = 0

    const unsigned short* pre = PRE + (size_t)b * S_ * 768;
    // rolling prefetch pointers (point at step s+1 inside the loop)
    const unsigned short* pA = pre + ((wid < 4) ? 128 : 256) + colA;  // xr|xz
    const unsigned short* pX = pre + 384 + colB;  // xh; fdir=+128; psi=+256
    const unsigned short* pD = pre + 768 + colB;  // decay[s+1]

    float c_p0, c_p1, c_xh, c_fd, c_ps, c_dk;
    {
        ushort2 t = *(const ushort2*)pA;
        c_p0 = bf2f(t.x); c_p1 = bf2f(t.y);
        c_xh = bf2f(pX[0]); c_fd = bf2f(pX[128]); c_ps = bf2f(pX[256]);
        c_dk = bf2f(pD[0]);
    }
    bar_lds();

    float hn = 0.f;
    for (int s = 0; s < S_; ++s) {
        // prefetch step s+1 constants (stay in vmcnt flight across barriers)
        pA += 768; pX += 768; pD += 768;
        ushort2 tn = *(const ushort2*)pA;
        unsigned short nx = pX[0], nf = pX[128], np = pX[256], nd = pD[0];

        // ---- P1: r/z matvec over hd, 4-way acc split + DPP quad reduce ----
        float2 hdA = *(const float2*)&hd[colA];   // for rh = sig(r)*hd
        float a0[4] = {0.f,0.f,0.f,0.f}, a1[4] = {0.f,0.f,0.f,0.f};
#pragma unroll
        for (int q = 0; q < 8; ++q) {
            float4 hv = *(const float4*)&hd[16 * q + 4 * kg];
            int m = q & 3;
            a0[m] = fmaf(hv.x, wrz[(q*4+0)*2+0], a0[m]); a1[m] = fmaf(hv.x, wrz[(q*4+0)*2+1], a1[m]);
            a0[m] = fmaf(hv.y, wrz[(q*4+1)*2+0], a0[m]); a1[m] = fmaf(hv.y, wrz[(q*4+1)*2+1], a1[m]);
            a0[m] = fmaf(hv.z, wrz[(q*4+2)*2+0], a0[m]); a1[m] = fmaf(hv.z, wrz[(q*4+2)*2+1], a1[m]);
            a0[m] = fmaf(hv.w, wrz[(q*4+3)*2+0], a0[m]); a1[m] = fmaf(hv.w, wrz[(q*4+3)*2+1], a1[m]);
        }
        float s0 = (a0[0] + a0[1]) + (a0[2] + a0[3]);
        float s1 = (a1[0] + a1[1]) + (a1[2] + a1[3]);
        s0 = dppadd<0xB1>(s0); s0 = dppadd<0x4E>(s0);
        s1 = dppadd<0xB1>(s1); s1 = dppadd<0x4E>(s1);
        if (kg == 0) {
            float g0 = fsig(c_p0 + s0), g1 = fsig(c_p1 + s1);
            if (wid < 4) *(float2*)&rh[colA] = make_float2(g0 * hdA.x, g1 * hdA.y);
            else         *(float2*)&zb[colA] = make_float2(g0, g1);
        }
        bar_lds();   // rh, zb ready

        // ---- P2: h matvec over rh (all 8 waves) + update ----
        float z_  = zb[colB];
        float hd_ = hd[colB];
        float c2[4] = {0.f,0.f,0.f,0.f};
#pragma unroll
        for (int q = 0; q < 8; ++q) {
            float4 rv = *(const float4*)&rh[16 * q + 4 * kg];
            int m = q & 3;
            c2[m] = fmaf(rv.x, whh[q * 4 + 0], c2[m]);
            c2[m] = fmaf(rv.y, whh[q * 4 + 1], c2[m]);
            c2[m] = fmaf(rv.z, whh[q * 4 + 2], c2[m]);
            c2[m] = fmaf(rv.w, whh[q * 4 + 3], c2[m]);
        }
        float s2 = (c2[0] + c2[1]) + (c2[2] + c2[3]);
        s2 = dppadd<0xB1>(s2); s2 = dppadd<0x4E>(s2);
        float hb = ftanh(c_xh + s2);
        float hf = ftanh(hb + c_fd);
        float hc = (1.f - c_ps) * hb + c_ps * hf;
        hn = (1.f - z_) * hd_ + z_ * hc;          // alpha==1 -> h_att = h_d
        if (kg == 0) hd[colB] = c_dk * hn;        // decay[s+1] * h_new
        bar_lds();   // hd ready for next step

        c_p0 = bf2f(tn.x); c_p1 = bf2f(tn.y);
        c_xh = bf2f(nx); c_fd = bf2f(nf); c_ps = bf2f(np); c_dk = bf2f(nd);
    }
    if (kg == 0) Hb[(size_t)b * U_ + colB] = f2bf(hn);
}

// ---------------------------------------------------------------------------
// k4a: logits = h @ W_out + b_out via bf16 MFMA.
__global__ __launch_bounds__(256) void k4a_logits(
    const unsigned short* __restrict__ Hb, const unsigned short* __restrict__ WT,
    const float* __restrict__ b_out, float* __restrict__ logits)
{
    const int tid  = threadIdx.x;
    const int lane = tid & 63, wid = tid >> 6;
    const int quad = lane >> 4, l16 = lane & 15;
    const int rb = blockIdx.y * 64 + wid * 16;
    const int cb = blockIdx.x * 128;

    short8v av[4];
#pragma unroll
    for (int kb = 0; kb < 4; ++kb)
        av[kb] = *(const short8v*)&Hb[(size_t)(rb + l16) * 128 + kb * 32 + quad * 8];

    float4v acc[8];
#pragma unroll
    for (int i = 0; i < 8; ++i) acc[i] = (float4v)0.0f;

#pragma unroll
    for (int kb = 0; kb < 4; ++kb) {
#pragma unroll
        for (int nt = 0; nt < 8; ++nt) {
            short8v bv = *(const short8v*)&WT[(size_t)(cb + nt * 16 + l16) * 128 + kb * 32 + quad * 8];
            acc[nt] = __builtin_amdgcn_mfma_f32_16x16x32_bf16(av[kb], bv, acc[nt], 0, 0, 0);
        }
    }
#pragma unroll
    for (int nt = 0; nt < 8; ++nt) {
        int n = cb + nt * 16 + l16;
        if (n < NC) {
            float bb = b_out[n];
#pragma unroll
            for (int r = 0; r < 4; ++r)
                logits[(size_t)(rb + quad * 4 + r) * NC + n] = acc[nt][r] + bb;
        }
    }
}

// ---------------------------------------------------------------------------
__global__ __launch_bounds__(256) void k4b_rowstats(
    const float* __restrict__ logits, float* __restrict__ rmax, float* __restrict__ rsum)
{
    const int r = blockIdx.x;
    const int tid = threadIdx.x;
    const float* row = logits + (size_t)r * NC;

    float m = -INFINITY, s = 0.f;
    for (int c = tid; c < NC; c += 256) {
        float x = row[c];
        float mn = fmaxf(m, x);
        s = s * expf(m - mn) + expf(x - mn);
        m = mn;
    }
    __shared__ float sm[256], ss[256];
    sm[tid] = m; ss[tid] = s;
    __syncthreads();
    for (int off = 128; off > 0; off >>= 1) {
        if (tid < off) {
            float m2 = sm[tid + off], s2 = ss[tid + off];
            float M = fmaxf(sm[tid], m2);
            ss[tid] = ss[tid] * expf(sm[tid] - M) + s2 * expf(m2 - M);
            sm[tid] = M;
        }
        __syncthreads();
    }
    if (tid == 0) { rmax[r] = sm[0]; rsum[r] = ss[0]; }
}

__global__ __launch_bounds__(256) void k4c_norm(
    const float* __restrict__ logits, const float* __restrict__ rmax,
    const float* __restrict__ rsum, float* __restrict__ out)
{
    const int r = blockIdx.y;
    const int c = blockIdx.x * 256 + threadIdx.x;
    if (c < NC) {
        size_t i = (size_t)r * NC + c;
        out[i] = expf(logits[i] - rmax[r]) / rsum[r];
    }
}

// ---------------------------------------------------------------------------
extern "C" void kernel_launch(void* const* d_in, const int* in_sizes, int n_in,
                              void* d_out, int out_size, void* d_ws, size_t ws_size,
                              hipStream_t stream) {
    const int*   item   = (const int*)d_in[0];
    const int*   tix    = (const int*)d_in[1];
    const int*   frq    = (const int*)d_in[2];
    const float* Ei     = (const float*)d_in[3];
    const float* Et     = (const float*)d_in[4];
    const float* Ef     = (const float*)d_in[5];
    const float* W_xr   = (const float*)d_in[6];
    const float* W_hr   = (const float*)d_in[7];
    const float* b_r    = (const float*)d_in[8];
    const float* W_xz   = (const float*)d_in[9];
    const float* W_hz   = (const float*)d_in[10];
    const float* b_z    = (const float*)d_in[11];
    const float* W_xh   = (const float*)d_in[12];
    const float* W_hh   = (const float*)d_in[13];
    const float* b_h    = (const float*)d_in[14];
    const float* W_xtg  = (const float*)d_in[15];
    const float* W_tg   = (const float*)d_in[16];
    const float* b_tg   = (const float*)d_in[17];
    const float* W_xfg  = (const float*)d_in[18];
    const float* W_fg   = (const float*)d_in[19];
    const float* b_fg   = (const float*)d_in[20];
    const float* W_delta= (const float*)d_in[21];
    const float* b_delta= (const float*)d_in[22];
    const float* W_f_dir= (const float*)d_in[23];
    const float* b_f_dir= (const float*)d_in[24];
    const float* W_psi  = (const float*)d_in[25];
    const float* b_psi  = (const float*)d_in[26];
    // d_in[27] = W_a — dead (softmax over singleton axis == 1)
    const float* W_out  = (const float*)d_in[28];
    const float* b_out  = (const float*)d_in[29];
    float* out = (float*)d_out;

    float* ws   = (float*)d_ws;
    unsigned short* PRE = (unsigned short*)(ws + PRE_OFF);    // bf16 PRE
    float* LOG  = ws + LOG_OFF;
    unsigned short* WSWZ = (unsigned short*)(ws + WSWZ_OFF);
    unsigned short* WT   = (unsigned short*)(ws + PRE_OFF);   // aliases PRE (dead after k3)
    unsigned short* Hb   = (unsigned short*)(ws + HF_OFF);
    float* RMAX = ws + RMAX_OFF;
    float* RSUM = ws + RSUM_OFF;

    k0_wconv<<<12, 256, 0, stream>>>(
        W_xtg, W_tg, W_xfg, W_fg, W_xr, W_xz, W_xh,
        W_delta, W_delta + 128 * 128, W_f_dir, W_psi,
        W_psi /* pad slot 11, unused by k12 */, WSWZ);
    k12_precompute<<<NTOK / 64, 256, 0, stream>>>(
        item, tix, frq, Ei, Et, Ef,
        b_r, b_z, b_h, b_tg, b_fg, b_delta, b_f_dir, b_psi,
        WSWZ, PRE);
    k3_scan<<<B_, 512, 0, stream>>>(PRE, W_hr, W_hz, W_hh, Hb);
    k0b_woutT<<<(NC + 63) / 64, 256, 0, stream>>>(W_out, WT);
    k4a_logits<<<dim3((NC + 127) / 128, B_ / 64), 256, 0, stream>>>(Hb, WT, b_out, LOG);
    k4b_rowstats<<<B_, 256, 0, stream>>>(LOG, RMAX, RSUM);
    k4c_norm<<<dim3((NC + 255) / 256, B_), 256, 0, stream>>>(LOG, RMAX, RSUM, out);
}

// Round 7
// 550.307 us; speedup vs baseline: 1.4277x; 1.1209x over previous
//
#include <hip/hip_runtime.h>
#include <math.h>

// ---------------------------------------------------------------------------
// LongRec.  B=256, S=200, D=U=128, NC=50000.
// alpha = softmax over singleton axis == 1.0 -> h_att = h_d; W_a is dead.
// Pipeline (6 kernels):
//   k0_prep : blocks 0-11: 128x128 weights fp32 -> bf16 k-swizzled B-frags;
//             blocks 12+: W_out -> bf16 WT[n][k] (own ws region now).
//   k12 : MFMA precompute -> PRE bf16 (reg A-frag gather; fast sigmoid;
//         decay = exp(-softplus(y)) == sigmoid(-y)).
//   k3  : 200-step recurrence, 1 wg/row, 512 thr = 8 waves; quad-DPP
//         reductions; 4-way acc split; bf16 PRE; 2 lgkm barriers/step.
//         ~198us floor across R3/R4/R6 variants — parked.
//   k4a : logits = h @ W_out + b_out via bf16 MFMA -> **bf16** logits
//         (logit scale ~0.03 -> bf16 error ~2e-9 on output; DPP lane-pair
//         packs 2 bf16 per dword store).
//   k4b : row max/sum, short8v vectorized bf16 loads.
//   k4c : normalize, short8v loads + float4 stores.
// ---------------------------------------------------------------------------

#define B_  256
#define S_  200
#define U_  128
#define NC  50000
#define NTOK (B_ * S_)       // 51200

// ws layout (in floats).
#define PRE_OFF   0
#define PRE_FL    (NTOK * 768 / 2)            // bf16 PRE: 19,660,800 floats
#define LOG_OFF   PRE_FL                      // bf16 logits: B_*NC/2 = 6.4M floats
#define WSWZ_OFF  (LOG_OFF + (B_ * NC / 2))   // 12*16384 ushort = 98304 floats
#define WT_OFF    (WSWZ_OFF + 98304)          // bf16 W_out^T: NC*U_/2 = 3.2M floats
#define HF_OFF    (WT_OFF + (NC * U_ / 2))    // Hb: B_*U_ ushort
#define RMAX_OFF  (HF_OFF + (B_ * U_ / 2))
#define RSUM_OFF  (RMAX_OFF + B_)

// PRE per-token layout (ushort idx): [decay(0)|xr(128)|xz(256)|xh(384)|fdir(512)|psi(640)]

typedef float  float4v  __attribute__((ext_vector_type(4)));
typedef short  short8v  __attribute__((ext_vector_type(8)));

// fast transcendentals: v_exp_f32 (2^x) + v_rcp_f32, ~2-3 ULP, branchless.
__device__ __forceinline__ float fsig(float x) {      // 1/(1+e^-x)
    return __builtin_amdgcn_rcpf(1.f + __builtin_amdgcn_exp2f(-1.4426950408889634f * x));
}
__device__ __forceinline__ float ftanh(float x) {     // 1 - 2/(e^{2x}+1)
    return 1.f - 2.f * __builtin_amdgcn_rcpf(1.f + __builtin_amdgcn_exp2f(2.8853900817779268f * x));
}
__device__ __forceinline__ unsigned short f2bf(float f) {   // RNE
    unsigned int u = __float_as_uint(f);
    u = (u + 0x7fffu + ((u >> 16) & 1u)) >> 16;
    return (unsigned short)u;
}
__device__ __forceinline__ unsigned int pack2bf(float a, float b) {
    return (unsigned int)f2bf(a) | ((unsigned int)f2bf(b) << 16);
}
__device__ __forceinline__ float bf2f(unsigned short u) {
    return __uint_as_float((unsigned int)u << 16);
}
// Barrier draining only LDS (lgkmcnt) — global prefetches stay in flight.
__device__ __forceinline__ void bar_lds() {
    asm volatile("s_waitcnt lgkmcnt(0)\n\ts_barrier" ::: "memory");
}
// VALU cross-lane via DPP quad_perm: 0xB1 = xor1, 0x4E = xor2.
template<int CTRL>
__device__ __forceinline__ float dppadd(float x) {
    return x + __int_as_float(
        __builtin_amdgcn_mov_dpp(__float_as_int(x), CTRL, 0xF, 0xF, true));
}
__device__ __forceinline__ float dppxor1(float x) {   // value from lane^1
    return __int_as_float(
        __builtin_amdgcn_mov_dpp(__float_as_int(x), 0xB1, 0xF, 0xF, true));
}

// ---------------------------------------------------------------------------
// k0_prep: blocks 0-11: [128][128] fp32 -> bf16 swizzled
//          dst[((k>>5)*128 + n)*32 + (k&31)];
//          blocks 12..: W_out [128][50000] fp32 -> WT [n][k] bf16.
__global__ __launch_bounds__(256) void k0_prep(
    const float* s0, const float* s1, const float* s2, const float* s3,
    const float* s4, const float* s5, const float* s6, const float* s7,
    const float* s8, const float* s9, const float* s10, const float* s11,
    const float* __restrict__ W_out,
    unsigned short* __restrict__ dst, unsigned short* __restrict__ WT)
{
    const int bid = blockIdx.x;
    if (bid < 12) {
        const float* srcs[12] = { s0,s1,s2,s3,s4,s5,s6,s7,s8,s9,s10,s11 };
        const float* S = srcs[bid];
        unsigned short* D = dst + (size_t)bid * 16384;
        for (int i = threadIdx.x; i < 16384; i += 256) {
            int k5 = i & 31, n = (i >> 5) & 127, kb = i >> 12;
            D[i] = f2bf(S[(size_t)(kb * 32 + k5) * 128 + n]);
        }
    } else {
        int n  = (bid - 12) * 64 + (threadIdx.x >> 2);
        int k0 = (threadIdx.x & 3) * 32;
        if (n >= NC) return;
#pragma unroll 8
        for (int i = 0; i < 32; ++i)
            WT[(size_t)n * 128 + k0 + i] = f2bf(W_out[(size_t)(k0 + i) * NC + n]);
    }
}

// ---------------------------------------------------------------------------
// MFMA helpers (16x16x32 bf16).  A-frag: lane holds A[m0+(lane&15)][kb*32+quad*8+j].
// B-frag (swizzled W): lane holds W[kb*32+quad*8+j][nt*16+(lane&15)].
// C/D: col = lane&15, row = quad*4 + reg.
__device__ __forceinline__ void gemm_k128(const unsigned short (*A)[136],
                                          int m0, int l16, int quad,
                                          const unsigned short* __restrict__ Wm,
                                          float4v acc[8]) {
#pragma unroll
    for (int kb = 0; kb < 4; ++kb) {
        short8v av = *(const short8v*)&A[m0 + l16][kb * 32 + quad * 8];
#pragma unroll
        for (int nt = 0; nt < 8; ++nt) {
            short8v bv = *(const short8v*)(Wm + (((kb * 128) + nt * 16 + l16) * 32 + quad * 8));
            acc[nt] = __builtin_amdgcn_mfma_f32_16x16x32_bf16(av, bv, acc[nt], 0, 0, 0);
        }
    }
}
// A-frags held in registers (gathered directly from the embedding tables).
__device__ __forceinline__ void gemm_reg(const short8v a[4], int l16, int quad,
                                         const unsigned short* __restrict__ Wm,
                                         float4v acc[8]) {
#pragma unroll
    for (int kb = 0; kb < 4; ++kb) {
#pragma unroll
        for (int nt = 0; nt < 8; ++nt) {
            short8v bv = *(const short8v*)(Wm + (((kb * 128) + nt * 16 + l16) * 32 + quad * 8));
            acc[nt] = __builtin_amdgcn_mfma_f32_16x16x32_bf16(a[kb], bv, acc[nt], 0, 0, 0);
        }
    }
}
__device__ __forceinline__ void zero8(float4v acc[8]) {
#pragma unroll
    for (int i = 0; i < 8; ++i) acc[i] = (float4v)0.0f;
}
// 8 contiguous f32 -> one bf16 A-frag word (16B)
__device__ __forceinline__ short8v cvt8(const float* __restrict__ p) {
    float4 v0 = *(const float4*)p;
    float4 v1 = *(const float4*)(p + 4);
    union { unsigned int u[4]; short8v s; } r;
    r.u[0] = pack2bf(v0.x, v0.y);
    r.u[1] = pack2bf(v0.z, v0.w);
    r.u[2] = pack2bf(v1.x, v1.y);
    r.u[3] = pack2bf(v1.z, v1.w);
    return r.s;
}

// ---------------------------------------------------------------------------
// k12: fused MFMA precompute.  grid = NTOK/64, block = 256 (4 waves),
// wave w owns tokens t0+16w .. t0+16w+15.  No barriers (all LDS is wave-local).
// PRE written as bf16.
__global__ __launch_bounds__(256, 4) void k12_precompute(
    const int* __restrict__ item, const int* __restrict__ tix, const int* __restrict__ frq,
    const float* __restrict__ Ei, const float* __restrict__ Et, const float* __restrict__ Ef,
    const float* __restrict__ b_r, const float* __restrict__ b_z, const float* __restrict__ b_h,
    const float* __restrict__ b_tg, const float* __restrict__ b_fg,
    const float* __restrict__ b_delta, const float* __restrict__ b_f_dir, const float* __restrict__ b_psi,
    const unsigned short* __restrict__ WZ,
    unsigned short* __restrict__ PRE)
{
    __shared__ unsigned short Atg[64][136];   // tg (bf16, A-layout)
    __shared__ unsigned short Afg[64][136];   // fg (bf16, A-layout)

    const int t0   = blockIdx.x * 64;
    const int tid  = threadIdx.x;
    const int lane = tid & 63;
    const int wid  = tid >> 6;
    const int quad = lane >> 4;
    const int l16  = lane & 15;
    const int m0   = wid * 16;

    // --- gather embedding rows straight into register A-frags ---
    const int tok = t0 + m0 + l16;
    const int it  = item[tok], tt = tix[tok], ft = frq[tok];
    const float* pei = Ei + (size_t)it * U_ + quad * 8;
    const float* pet = Et + (size_t)tt * U_ + quad * 8;
    const float* pef = Ef + (size_t)ft * U_ + quad * 8;

    short8v axi[4], axt[4], axf[4];
#pragma unroll
    for (int kb = 0; kb < 4; ++kb) axi[kb] = cvt8(pei + kb * 32);
#pragma unroll
    for (int kb = 0; kb < 4; ++kb) axt[kb] = cvt8(pet + kb * 32);
#pragma unroll
    for (int kb = 0; kb < 4; ++kb) axf[kb] = cvt8(pef + kb * 32);

    const unsigned short* WM0  = WZ;                 // W_xtg
    const unsigned short* WM1  = WZ + 1  * 16384;    // W_tg
    const unsigned short* WM2  = WZ + 2  * 16384;    // W_xfg
    const unsigned short* WM3  = WZ + 3  * 16384;    // W_fg
    const unsigned short* WM4  = WZ + 4  * 16384;    // W_xr
    const unsigned short* WM5  = WZ + 5  * 16384;    // W_xz
    const unsigned short* WM6  = WZ + 6  * 16384;    // W_xh
    const unsigned short* WM7  = WZ + 7  * 16384;    // W_delta top (tg rows)
    const unsigned short* WM8  = WZ + 8  * 16384;    // W_delta bot (fg rows)
    const unsigned short* WM9  = WZ + 9  * 16384;    // W_f_dir
    const unsigned short* WM10 = WZ + 10 * 16384;    // W_psi

    float4v acc[8];
    const int tokbase = t0 + m0 + quad * 4;

    // ---- tg = sigmoid(xi@W_xtg + xt@W_tg + b_tg) -> Atg (bf16, A-layout) ----
    zero8(acc);
    gemm_reg(axi, l16, quad, WM0, acc);
    gemm_reg(axt, l16, quad, WM1, acc);
#pragma unroll
    for (int nt = 0; nt < 8; ++nt) {
        int n = nt * 16 + l16;
        float bb = b_tg[n];
#pragma unroll
        for (int r = 0; r < 4; ++r)
            Atg[m0 + quad * 4 + r][n] = f2bf(fsig(acc[nt][r] + bb));
    }
    // ---- fg = sigmoid(xi@W_xfg + xf@W_fg + b_fg) -> Afg ----
    zero8(acc);
    gemm_reg(axi, l16, quad, WM2, acc);
    gemm_reg(axf, l16, quad, WM3, acc);
#pragma unroll
    for (int nt = 0; nt < 8; ++nt) {
        int n = nt * 16 + l16;
        float bb = b_fg[n];
#pragma unroll
        for (int r = 0; r < 4; ++r)
            Afg[m0 + quad * 4 + r][n] = f2bf(fsig(acc[nt][r] + bb));
    }

    // ---- xr, xz, xh (xi only — hides the Atg/Afg LDS write->read latency) ----
    {
        const unsigned short* Wx[3] = { WM4, WM5, WM6 };
        const float* bx[3] = { b_r, b_z, b_h };
        const int    off[3] = { 128, 256, 384 };
#pragma unroll
        for (int m = 0; m < 3; ++m) {
            zero8(acc);
            gemm_reg(axi, l16, quad, Wx[m], acc);
#pragma unroll
            for (int nt = 0; nt < 8; ++nt) {
                int n = nt * 16 + l16;
                float bb = bx[m][n];
#pragma unroll
                for (int r = 0; r < 4; ++r)
                    PRE[(size_t)(tokbase + r) * 768 + off[m] + n] = f2bf(acc[nt][r] + bb);
            }
        }
    }
    // ---- decay = exp(-softplus(y)) == sigmoid(-y), y = [tg|fg]@W_delta + b ----
    zero8(acc);
    gemm_k128(Atg, m0, l16, quad, WM7, acc);
    gemm_k128(Afg, m0, l16, quad, WM8, acc);
#pragma unroll
    for (int nt = 0; nt < 8; ++nt) {
        int n = nt * 16 + l16;
        float bb = b_delta[n];
#pragma unroll
        for (int r = 0; r < 4; ++r)
            PRE[(size_t)(tokbase + r) * 768 + 0 + n] = f2bf(fsig(-(acc[nt][r] + bb)));
    }
    // ---- fdir = fg@W_f_dir + b ----
    zero8(acc);
    gemm_k128(Afg, m0, l16, quad, WM9, acc);
#pragma unroll
    for (int nt = 0; nt < 8; ++nt) {
        int n = nt * 16 + l16;
        float bb = b_f_dir[n];
#pragma unroll
        for (int r = 0; r < 4; ++r)
            PRE[(size_t)(tokbase + r) * 768 + 512 + n] = f2bf(acc[nt][r] + bb);
    }
    // ---- psi = sigmoid(fg@W_psi + b) ----
    zero8(acc);
    gemm_k128(Afg, m0, l16, quad, WM10, acc);
#pragma unroll
    for (int nt = 0; nt < 8; ++nt) {
        int n = nt * 16 + l16;
        float bb = b_psi[n];
#pragma unroll
        for (int r = 0; r < 4; ++r)
            PRE[(size_t)(tokbase + r) * 768 + 640 + n] = f2bf(fsig(acc[nt][r] + bb));
    }
}

// ---------------------------------------------------------------------------
// k3: one workgroup per batch row; 512 threads = 8 waves (R6 structure —
// measured floor ~198us; VALUBusy 57%, rest is 2x(LDS latency + barrier)).
__global__ __launch_bounds__(512, 2) void k3_scan(
    const unsigned short* __restrict__ PRE,
    const float* __restrict__ W_hr, const float* __restrict__ W_hz, const float* __restrict__ W_hh,
    unsigned short* __restrict__ Hb)
{
    const int b    = blockIdx.x;
    const int tid  = threadIdx.x;
    const int lane = tid & 63;
    const int wid  = tid >> 6;          // 0..7
    const int cp   = lane >> 2;         // 0..15 (col selector)
    const int kg   = lane & 3;          // 0..3  (k-group = quad lane)

    const int colA = ((wid & 3) << 5) + (cp << 1);   // P1: 2 cols (even)
    const int colB = (wid << 4) + cp;                // P2: 1 col

    // --- loop-invariant weights pinned in VGPRs ---
    const float* Wrz = (wid < 4) ? W_hr : W_hz;
    float wrz[64];   // [(q*4+j)*2+c] = Wrz[16q+4kg+j][colA+c]
#pragma unroll
    for (int q = 0; q < 8; ++q)
#pragma unroll
        for (int j = 0; j < 4; ++j) {
            float2 wv = *(const float2*)&Wrz[(size_t)(16 * q + 4 * kg + j) * U_ + colA];
            wrz[(q * 4 + j) * 2 + 0] = wv.x;
            wrz[(q * 4 + j) * 2 + 1] = wv.y;
        }
    float whh[32];   // [q*4+j] = W_hh[16q+4kg+j][colB]
#pragma unroll
    for (int q = 0; q < 8; ++q)
#pragma unroll
        for (int j = 0; j < 4; ++j)
            whh[q * 4 + j] = W_hh[(size_t)(16 * q + 4 * kg + j) * U_ + colB];
#pragma unroll
    for (int k = 0; k < 64; ++k) asm volatile("" : "+v"(wrz[k]));
#pragma unroll
    for (int k = 0; k < 32; ++k) asm volatile("" : "+v"(whh[k]));

    __shared__ __align__(16) float hd[U_];
    __shared__ __align__(16) float rh[U_];
    __shared__ __align__(16) float zb[U_];
    if (tid < U_) hd[tid] = 0.f;    // h0 = 0 -> h_d(step 0) = 0

    const unsigned short* pre = PRE + (size_t)b * S_ * 768;
    // rolling prefetch pointers (point at step s+1 inside the loop)
    const unsigned short* pA = pre + ((wid < 4) ? 128 : 256) + colA;  // xr|xz
    const unsigned short* pX = pre + 384 + colB;  // xh; fdir=+128; psi=+256
    const unsigned short* pD = pre + 768 + colB;  // decay[s+1]

    float c_p0, c_p1, c_xh, c_fd, c_ps, c_dk;
    {
        ushort2 t = *(const ushort2*)pA;
        c_p0 = bf2f(t.x); c_p1 = bf2f(t.y);
        c_xh = bf2f(pX[0]); c_fd = bf2f(pX[128]); c_ps = bf2f(pX[256]);
        c_dk = bf2f(pD[0]);
    }
    bar_lds();

    float hn = 0.f;
    for (int s = 0; s < S_; ++s) {
        // prefetch step s+1 constants (stay in vmcnt flight across barriers)
        pA += 768; pX += 768; pD += 768;
        ushort2 tn = *(const ushort2*)pA;
        unsigned short nx = pX[0], nf = pX[128], np = pX[256], nd = pD[0];

        // ---- P1: r/z matvec over hd, 4-way acc split + DPP quad reduce ----
        float2 hdA = *(const float2*)&hd[colA];   // for rh = sig(r)*hd
        float a0[4] = {0.f,0.f,0.f,0.f}, a1[4] = {0.f,0.f,0.f,0.f};
#pragma unroll
        for (int q = 0; q < 8; ++q) {
            float4 hv = *(const float4*)&hd[16 * q + 4 * kg];
            int m = q & 3;
            a0[m] = fmaf(hv.x, wrz[(q*4+0)*2+0], a0[m]); a1[m] = fmaf(hv.x, wrz[(q*4+0)*2+1], a1[m]);
            a0[m] = fmaf(hv.y, wrz[(q*4+1)*2+0], a0[m]); a1[m] = fmaf(hv.y, wrz[(q*4+1)*2+1], a1[m]);
            a0[m] = fmaf(hv.z, wrz[(q*4+2)*2+0], a0[m]); a1[m] = fmaf(hv.z, wrz[(q*4+2)*2+1], a1[m]);
            a0[m] = fmaf(hv.w, wrz[(q*4+3)*2+0], a0[m]); a1[m] = fmaf(hv.w, wrz[(q*4+3)*2+1], a1[m]);
        }
        float s0 = (a0[0] + a0[1]) + (a0[2] + a0[3]);
        float s1 = (a1[0] + a1[1]) + (a1[2] + a1[3]);
        s0 = dppadd<0xB1>(s0); s0 = dppadd<0x4E>(s0);
        s1 = dppadd<0xB1>(s1); s1 = dppadd<0x4E>(s1);
        if (kg == 0) {
            float g0 = fsig(c_p0 + s0), g1 = fsig(c_p1 + s1);
            if (wid < 4) *(float2*)&rh[colA] = make_float2(g0 * hdA.x, g1 * hdA.y);
            else         *(float2*)&zb[colA] = make_float2(g0, g1);
        }
        bar_lds();   // rh, zb ready

        // ---- P2: h matvec over rh (all 8 waves) + update ----
        float z_  = zb[colB];
        float hd_ = hd[colB];
        float c2[4] = {0.f,0.f,0.f,0.f};
#pragma unroll
        for (int q = 0; q < 8; ++q) {
            float4 rv = *(const float4*)&rh[16 * q + 4 * kg];
            int m = q & 3;
            c2[m] = fmaf(rv.x, whh[q * 4 + 0], c2[m]);
            c2[m] = fmaf(rv.y, whh[q * 4 + 1], c2[m]);
            c2[m] = fmaf(rv.z, whh[q * 4 + 2], c2[m]);
            c2[m] = fmaf(rv.w, whh[q * 4 + 3], c2[m]);
        }
        float s2 = (c2[0] + c2[1]) + (c2[2] + c2[3]);
        s2 = dppadd<0xB1>(s2); s2 = dppadd<0x4E>(s2);
        float hb = ftanh(c_xh + s2);
        float hf = ftanh(hb + c_fd);
        float hc = (1.f - c_ps) * hb + c_ps * hf;
        hn = (1.f - z_) * hd_ + z_ * hc;          // alpha==1 -> h_att = h_d
        if (kg == 0) hd[colB] = c_dk * hn;        // decay[s+1] * h_new
        bar_lds();   // hd ready for next step

        c_p0 = bf2f(tn.x); c_p1 = bf2f(tn.y);
        c_xh = bf2f(nx); c_fd = bf2f(nf); c_ps = bf2f(np); c_dk = bf2f(nd);
    }
    if (kg == 0) Hb[(size_t)b * U_ + colB] = f2bf(hn);
}

// ---------------------------------------------------------------------------
// k4a: logits = h @ W_out + b_out via bf16 MFMA -> bf16 logits.
// DPP lane-pairing: even l16 lane packs (its value, lane^1's value) -> dword.
__global__ __launch_bounds__(256) void k4a_logits(
    const unsigned short* __restrict__ Hb, const unsigned short* __restrict__ WT,
    const float* __restrict__ b_out, unsigned short* __restrict__ LOGb)
{
    const int tid  = threadIdx.x;
    const int lane = tid & 63, wid = tid >> 6;
    const int quad = lane >> 4, l16 = lane & 15;
    const int rb = blockIdx.y * 64 + wid * 16;
    const int cb = blockIdx.x * 128;

    short8v av[4];
#pragma unroll
    for (int kb = 0; kb < 4; ++kb)
        av[kb] = *(const short8v*)&Hb[(size_t)(rb + l16) * 128 + kb * 32 + quad * 8];

    float4v acc[8];
#pragma unroll
    for (int i = 0; i < 8; ++i) acc[i] = (float4v)0.0f;

#pragma unroll
    for (int kb = 0; kb < 4; ++kb) {
#pragma unroll
        for (int nt = 0; nt < 8; ++nt) {
            short8v bv = *(const short8v*)&WT[(size_t)(cb + nt * 16 + l16) * 128 + kb * 32 + quad * 8];
            acc[nt] = __builtin_amdgcn_mfma_f32_16x16x32_bf16(av[kb], bv, acc[nt], 0, 0, 0);
        }
    }
#pragma unroll
    for (int nt = 0; nt < 8; ++nt) {
        int n = cb + nt * 16 + l16;
        float bb = (n < NC) ? b_out[n] : 0.f;
#pragma unroll
        for (int r = 0; r < 4; ++r) {
            float v  = acc[nt][r] + bb;
            float vn = dppxor1(v);                 // lane^1's value (col n^1)
            if (((l16 & 1) == 0) && n < NC) {      // NC even -> n+1 < NC too
                *(unsigned int*)((char*)LOGb +
                    ((size_t)(rb + quad * 4 + r) * NC + n) * 2) = pack2bf(v, vn);
            }
        }
    }
}

// ---------------------------------------------------------------------------
// k4b: row max/sum over bf16 logits, short8v vector loads (NC/8 = 6250 chunks).
__global__ __launch_bounds__(256) void k4b_rowstats(
    const unsigned short* __restrict__ LOGb, float* __restrict__ rmax, float* __restrict__ rsum)
{
    const int r = blockIdx.x;
    const int tid = threadIdx.x;
    const unsigned short* row = LOGb + (size_t)r * NC;

    float m = -INFINITY, s = 0.f;
    for (int c8 = tid; c8 < NC / 8; c8 += 256) {
        short8v v = *(const short8v*)(row + c8 * 8);
        float x[8];
#pragma unroll
        for (int j = 0; j < 8; ++j) x[j] = bf2f((unsigned short)v[j]);
        float m8 = fmaxf(fmaxf(fmaxf(x[0], x[1]), fmaxf(x[2], x[3])),
                         fmaxf(fmaxf(x[4], x[5]), fmaxf(x[6], x[7])));
        float mn = fmaxf(m, m8);
        s = s * expf(m - mn);
#pragma unroll
        for (int j = 0; j < 8; ++j) s += expf(x[j] - mn);
        m = mn;
    }
    __shared__ float sm[256], ss[256];
    sm[tid] = m; ss[tid] = s;
    __syncthreads();
    for (int off = 128; off > 0; off >>= 1) {
        if (tid < off) {
            float m2 = sm[tid + off], s2 = ss[tid + off];
            float M = fmaxf(sm[tid], m2);
            ss[tid] = ss[tid] * expf(sm[tid] - M) + s2 * expf(m2 - M);
            sm[tid] = M;
        }
        __syncthreads();
    }
    if (tid == 0) { rmax[r] = sm[0]; rsum[r] = ss[0]; }
}

// ---------------------------------------------------------------------------
// k4c: out = exp(l - rmax)/rsum, 8 elements/thread (short8v in, 2x float4 out).
__global__ __launch_bounds__(256) void k4c_norm(
    const unsigned short* __restrict__ LOGb, const float* __restrict__ rmax,
    const float* __restrict__ rsum, float* __restrict__ out)
{
    const int r  = blockIdx.y;
    const int c8 = blockIdx.x * 256 + threadIdx.x;
    if (c8 < NC / 8) {
        short8v v = *(const short8v*)(LOGb + (size_t)r * NC + c8 * 8);
        float mr  = rmax[r];
        float inv = 1.f / rsum[r];
        float4 o0, o1;
        o0.x = expf(bf2f((unsigned short)v[0]) - mr) * inv;
        o0.y = expf(bf2f((unsigned short)v[1]) - mr) * inv;
        o0.z = expf(bf2f((unsigned short)v[2]) - mr) * inv;
        o0.w = expf(bf2f((unsigned short)v[3]) - mr) * inv;
        o1.x = expf(bf2f((unsigned short)v[4]) - mr) * inv;
        o1.y = expf(bf2f((unsigned short)v[5]) - mr) * inv;
        o1.z = expf(bf2f((unsigned short)v[6]) - mr) * inv;
        o1.w = expf(bf2f((unsigned short)v[7]) - mr) * inv;
        float* po = out + (size_t)r * NC + c8 * 8;
        *(float4*)po       = o0;
        *(float4*)(po + 4) = o1;
    }
}

// ---------------------------------------------------------------------------
extern "C" void kernel_launch(void* const* d_in, const int* in_sizes, int n_in,
                              void* d_out, int out_size, void* d_ws, size_t ws_size,
                              hipStream_t stream) {
    const int*   item   = (const int*)d_in[0];
    const int*   tix    = (const int*)d_in[1];
    const int*   frq    = (const int*)d_in[2];
    const float* Ei     = (const float*)d_in[3];
    const float* Et     = (const float*)d_in[4];
    const float* Ef     = (const float*)d_in[5];
    const float* W_xr   = (const float*)d_in[6];
    const float* W_hr   = (const float*)d_in[7];
    const float* b_r    = (const float*)d_in[8];
    const float* W_xz   = (const float*)d_in[9];
    const float* W_hz   = (const float*)d_in[10];
    const float* b_z    = (const float*)d_in[11];
    const float* W_xh   = (const float*)d_in[12];
    const float* W_hh   = (const float*)d_in[13];
    const float* b_h    = (const float*)d_in[14];
    const float* W_xtg  = (const float*)d_in[15];
    const float* W_tg   = (const float*)d_in[16];
    const float* b_tg   = (const float*)d_in[17];
    const float* W_xfg  = (const float*)d_in[18];
    const float* W_fg   = (const float*)d_in[19];
    const float* b_fg   = (const float*)d_in[20];
    const float* W_delta= (const float*)d_in[21];
    const float* b_delta= (const float*)d_in[22];
    const float* W_f_dir= (const float*)d_in[23];
    const float* b_f_dir= (const float*)d_in[24];
    const float* W_psi  = (const float*)d_in[25];
    const float* b_psi  = (const float*)d_in[26];
    // d_in[27] = W_a — dead (softmax over singleton axis == 1)
    const float* W_out  = (const float*)d_in[28];
    const float* b_out  = (const float*)d_in[29];
    float* out = (float*)d_out;

    float* ws   = (float*)d_ws;
    unsigned short* PRE  = (unsigned short*)(ws + PRE_OFF);    // bf16 PRE
    unsigned short* LOGb = (unsigned short*)(ws + LOG_OFF);    // bf16 logits
    unsigned short* WSWZ = (unsigned short*)(ws + WSWZ_OFF);
    unsigned short* WT   = (unsigned short*)(ws + WT_OFF);
    unsigned short* Hb   = (unsigned short*)(ws + HF_OFF);
    float* RMAX = ws + RMAX_OFF;
    float* RSUM = ws + RSUM_OFF;

    k0_prep<<<12 + (NC + 63) / 64, 256, 0, stream>>>(
        W_xtg, W_tg, W_xfg, W_fg, W_xr, W_xz, W_xh,
        W_delta, W_delta + 128 * 128, W_f_dir, W_psi,
        W_psi /* pad slot 11, unused by k12 */,
        W_out, WSWZ, WT);
    k12_precompute<<<NTOK / 64, 256, 0, stream>>>(
        item, tix, frq, Ei, Et, Ef,
        b_r, b_z, b_h, b_tg, b_fg, b_delta, b_f_dir, b_psi,
        WSWZ, PRE);
    k3_scan<<<B_, 512, 0, stream>>>(PRE, W_hr, W_hz, W_hh, Hb);
    k4a_logits<<<dim3((NC + 127) / 128, B_ / 64), 256, 0, stream>>>(Hb, WT, b_out, LOGb);
    k4b_rowstats<<<B_, 256, 0, stream>>>(LOGb, RMAX, RSUM);
    k4c_norm<<<dim3((NC / 8 + 255) / 256, B_), 256, 0, stream>>>(LOGb, RMAX, RSUM, out);
}